// Round 1
// baseline (574.691 us; speedup 1.0000x reference)
//
#include <hip/hip_runtime.h>
#include <math.h>

// ---------------------------------------------------------------------------
// GAT IoT classifier — round 22: XCD-sliced aggregation.
// r19/r21 aggregate swept the whole 25.6 MB h-table through all 8 XCD L2s
// (FETCH 208.8 MB = 8x25.6 compulsory sweep, 67 us x2). This round:
//  - h stored block-major [8][Mp][32] (32-col slices, 3.2 MB each < 4 MB L2)
//  - aggregate split: stats kernel (per-node softmax m, 1/z; no h traffic)
//    + slice kernel with slice = blockIdx & 7 -> pinned to one XCD via
//    round-robin dispatch; each XCD gathers only its own L2-resident slice.
//  - GEMM epilogue writes C blocked; GEMM2/head read A blocked (same
//    coalescing). Numerics of p = exp(l-m)*inv identical to r19 path.
// Predicted: slice agg ~22-30 us each (FETCH ~70 MB), stats ~10 us each.
// ---------------------------------------------------------------------------

typedef __attribute__((ext_vector_type(8))) _Float16 half8v;  // 8 fp16 (4 VGPRs)
typedef __attribute__((ext_vector_type(4))) float f32x4;

__device__ __forceinline__ float lrelu(float x) { return x > 0.f ? x : 0.2f * x; }
__device__ __forceinline__ float elu1(float x) { return x > 0.f ? x : (__expf(x) - 1.f); }

// ---------------- weights -> transposed fp16 + indeg zeroing, one launch ------
__global__ void convert_weights_kernel(const float* __restrict__ W1, const float* __restrict__ W2,
                                       const float* __restrict__ lw1,
                                       _Float16* __restrict__ o1, _Float16* __restrict__ o2,
                                       _Float16* __restrict__ o3, int* __restrict__ indeg,
                                       int N) {
  int t = blockIdx.x * blockDim.x + threadIdx.x;
  if (t < 32768) {                       // W1
    int n = t >> 7, k = t & 127;
    o1[t] = (_Float16)W1[(long)k * 256 + n];
  } else if (t < 98304) {                // W2
    int i = t - 32768;
    int n = i >> 8, k = i & 255;
    o2[i] = (_Float16)W2[(long)k * 256 + n];
  } else if (t < 114688) {               // lw1
    int i = t - 98304;
    int n = i >> 8, k = i & 255;
    o3[i] = (_Float16)lw1[(long)k * 64 + n];
  } else if (t < 114688 + N) {           // indeg zeroing
    indeg[t - 114688] = 0;
  }
}

// ---------------- CSR build ----------------
__global__ void count_kernel(const int* __restrict__ dst, int E, int* __restrict__ indeg) {
  int e = blockIdx.x * blockDim.x + threadIdx.x;
  if (e < E) atomicAdd(&indeg[dst[e]], 1);
}

__global__ void scan_block_kernel(const int* __restrict__ in, int* __restrict__ incl,
                                  int* __restrict__ bsum, int N) {
  __shared__ int wsum[16];
  int gid = blockIdx.x * 1024 + threadIdx.x;
  int lane = threadIdx.x & 63, w = threadIdx.x >> 6;
  int v = (gid < N) ? in[gid] : 0;
  int sv = v;
#pragma unroll
  for (int o = 1; o < 64; o <<= 1) {
    int t = __shfl_up(sv, o);
    if (lane >= o) sv += t;
  }
  if (lane == 63) wsum[w] = sv;
  __syncthreads();
  if (w == 0) {
    int bs = (lane < 16) ? wsum[lane] : 0;
#pragma unroll
    for (int o = 1; o < 16; o <<= 1) {
      int t = __shfl_up(bs, o);
      if (lane >= o) bs += t;
    }
    if (lane < 16) wsum[lane] = bs;
  }
  __syncthreads();
  if (w > 0) sv += wsum[w - 1];
  if (gid < N) incl[gid] = sv;
  if (threadIdx.x == 1023) bsum[blockIdx.x] = sv;
}

__global__ void scan_finalize_kernel(const int* __restrict__ in, const int* __restrict__ incl,
                                     const int* __restrict__ bsum, int* __restrict__ off,
                                     int* __restrict__ cursor, int N) {
  int gid = blockIdx.x * blockDim.x + threadIdx.x;
  if (gid >= N) return;
  int b = gid >> 10;
  int carry = 0;
  for (int k = 0; k < b; ++k) carry += bsum[k];
  int ic = incl[gid] + carry;
  off[gid + 1] = ic;
  cursor[gid] = ic - in[gid];
  if (gid == 0) off[0] = 0;
}

__global__ void fill_kernel(const int* __restrict__ src, const int* __restrict__ dst, int E,
                            int* __restrict__ cursor, int* __restrict__ csr_src) {
  int e = blockIdx.x * blockDim.x + threadIdx.x;
  if (e < E) {
    int pos = atomicAdd(&cursor[dst[e]], 1);
    csr_src[pos] = src[e];
  }
}

// ---------------- fp16 MFMA GEMM (2 head blocks/block) + attn epilogue ----
// C[M,256] = A[M,K] x W[K,256]; W transposed [256][K].
// A: fp32 row-major (layer 1) or fp16 BLOCKED [8][Mp][32] (layer 2).
// C written BLOCKED [8][Mp][32] (col block = col>>5).
template <typename AT>
__launch_bounds__(256)
__global__ void mfma_gemm_attn_kernel(const AT* __restrict__ A,
                                      const _Float16* __restrict__ B,
                                      const float* __restrict__ att_s,
                                      const float* __restrict__ att_d,
                                      _Float16* __restrict__ C,
                                      float* __restrict__ a_s, float* __restrict__ a_d,
                                      int M, int K, int Mp) {
  __shared__ _Float16 As[64][40];     // 10.2+5.1 KB total: residency-safe
  __shared__ _Float16 Bs[2][64][40];
  int tid = threadIdx.x;
  int bm = blockIdx.y * 64, bn = blockIdx.x * 128;
  int lane = tid & 63, wave = tid >> 6;
  int srow = tid >> 2, sch = (tid & 3) * 8;
  const AT* Ap;
  if constexpr (sizeof(AT) == 4) {
    Ap = A + (long)(bm + srow) * K + sch;           // row-major fp32
  } else {
    Ap = A + (long)(bm + srow) * 32 + sch;          // blocked fp16
  }
  const _Float16* Bp0 = B + (long)(bn + srow) * K + sch;
  const _Float16* Bp1 = B + (long)(bn + 64 + srow) * K + sch;
  bool arow_ok = (bm + srow) < M;
  int fm = lane & 15, fq = lane >> 4;
  f32x4 acc[2][4];
#pragma unroll
  for (int t = 0; t < 2; ++t)
#pragma unroll
    for (int cb = 0; cb < 4; ++cb) acc[t][cb] = (f32x4){0.f, 0.f, 0.f, 0.f};
  for (int k0 = 0; k0 < K; k0 += 32) {
    half8v a8 = {0, 0, 0, 0, 0, 0, 0, 0};
    if (arow_ok) {
      if constexpr (sizeof(AT) == 4) {
        float4 f0 = *(const float4*)(Ap + k0);
        float4 f1 = *(const float4*)(Ap + k0 + 4);
        a8 = (half8v){(_Float16)f0.x, (_Float16)f0.y, (_Float16)f0.z, (_Float16)f0.w,
                      (_Float16)f1.x, (_Float16)f1.y, (_Float16)f1.z, (_Float16)f1.w};
      } else {
        a8 = *(const half8v*)(Ap + (long)(k0 >> 5) * Mp * 32);
      }
    }
    uint4 vb0 = *(const uint4*)(Bp0 + k0);
    uint4 vb1 = *(const uint4*)(Bp1 + k0);
    *(half8v*)&As[srow][sch] = a8;
    *(uint4*)&Bs[0][srow][sch] = vb0;
    *(uint4*)&Bs[1][srow][sch] = vb1;
    __syncthreads();
    half8v ah = *(const half8v*)&As[wave * 16 + fm][fq * 8];
#pragma unroll
    for (int t = 0; t < 2; ++t)
#pragma unroll
      for (int cb = 0; cb < 4; ++cb) {
        half8v bh = *(const half8v*)&Bs[t][cb * 16 + fm][fq * 8];
        acc[t][cb] = __builtin_amdgcn_mfma_f32_16x16x32_f16(ah, bh, acc[t][cb], 0, 0, 0);
      }
    __syncthreads();
  }
  int row0 = bm + wave * 16 + fq * 4;
#pragma unroll
  for (int t = 0; t < 2; ++t) {
    int headi = blockIdx.x * 2 + t;
    int cbase = bn + t * 64;
    float asv[4], adv[4];
#pragma unroll
    for (int cb = 0; cb < 4; ++cb) {
      int col = cbase + cb * 16 + fm;
      asv[cb] = att_s[col];
      adv[cb] = att_d[col];
    }
#pragma unroll
    for (int r = 0; r < 4; ++r) {
      int row = row0 + r;
      float sp = 0.f, dp = 0.f;
#pragma unroll
      for (int cb = 0; cb < 4; ++cb) {
        float v = acc[t][cb][r];
        sp = fmaf(v, asv[cb], sp);
        dp = fmaf(v, adv[cb], dp);
        if (row < M) {
          int col = cbase + cb * 16 + fm;
          C[((long)(col >> 5) * Mp + row) * 32 + (col & 31)] = (_Float16)v;
        }
      }
#pragma unroll
      for (int o = 1; o < 16; o <<= 1) {
        sp += __shfl_xor(sp, o);
        dp += __shfl_xor(dp, o);
      }
      if (fm == 0 && row < M) {
        a_s[(long)row * 4 + headi] = sp;
        a_d[(long)row * 4 + headi] = dp;
      }
    }
  }
}

// ---------------- fused fp16 MFMA head (A blocked) ----------------
__launch_bounds__(256)
__global__ void head_mfma_kernel(const _Float16* __restrict__ A, const _Float16* __restrict__ B,
                                 const float* __restrict__ lb1, const float* __restrict__ lw2,
                                 const float* __restrict__ lb2, float* __restrict__ out,
                                 int M, int Mp) {
  __shared__ _Float16 As[64][40];
  __shared__ _Float16 Bs[64][40];
  int tid = threadIdx.x;
  int bm = blockIdx.x * 64;
  int lane = tid & 63, wave = tid >> 6;
  int srow = tid >> 2, sch = (tid & 3) * 8;
  const _Float16* Ap = A + (long)(bm + srow) * 32 + sch;  // blocked [8][Mp][32]
  const _Float16* Bp = B + (long)srow * 256 + sch;
  int fm = lane & 15, fq = lane >> 4;
  f32x4 acc[4];
#pragma unroll
  for (int cb = 0; cb < 4; ++cb) acc[cb] = (f32x4){0.f, 0.f, 0.f, 0.f};
  for (int k0 = 0; k0 < 256; k0 += 32) {
    uint4 va = *(const uint4*)(Ap + (long)(k0 >> 5) * Mp * 32);
    uint4 vb = *(const uint4*)(Bp + k0);
    *(uint4*)&As[srow][sch] = va;
    *(uint4*)&Bs[srow][sch] = vb;
    __syncthreads();
    half8v ah = *(const half8v*)&As[wave * 16 + fm][fq * 8];
#pragma unroll
    for (int cb = 0; cb < 4; ++cb) {
      half8v bh = *(const half8v*)&Bs[cb * 16 + fm][fq * 8];
      acc[cb] = __builtin_amdgcn_mfma_f32_16x16x32_f16(ah, bh, acc[cb], 0, 0, 0);
    }
    __syncthreads();
  }
  float lb1c[4], w20[4], w21[4];
#pragma unroll
  for (int cb = 0; cb < 4; ++cb) {
    int col = cb * 16 + fm;
    lb1c[cb] = lb1[col];
    w20[cb] = lw2[col * 2 + 0];
    w21[cb] = lw2[col * 2 + 1];
  }
  float b20 = lb2[0], b21 = lb2[1];
#pragma unroll
  for (int r = 0; r < 4; ++r) {
    float v0 = 0.f, v1 = 0.f;
#pragma unroll
    for (int cb = 0; cb < 4; ++cb) {
      float s = fmaxf(acc[cb][r] + lb1c[cb], 0.f);
      v0 = fmaf(s, w20[cb], v0);
      v1 = fmaf(s, w21[cb], v1);
    }
#pragma unroll
    for (int o = 1; o < 16; o <<= 1) {
      v0 += __shfl_xor(v0, o);
      v1 += __shfl_xor(v1, o);
    }
    if (fm == 0) {
      int row = bm + wave * 16 + fq * 4 + r;
      if (row < M) {
        v0 += b20;
        v1 += b21;
        float mx = fmaxf(v0, v1);
        float ls = mx + logf(expf(v0 - mx) + expf(v1 - mx));
        out[(long)row * 2 + 0] = v0 - ls;
        out[(long)row * 2 + 1] = v1 - ls;
      }
    }
  }
}

// ---------------- phase A: per-node online-softmax stats (m, 1/z) ----------
// One wave per node. lane = slot*4 + head. Gathers only a_s (800 KB, L2-hot).
__launch_bounds__(256)
__global__ void attn_softmax_stats_kernel(const float* __restrict__ a_s,
                                          const float* __restrict__ a_d,
                                          const int* __restrict__ off,
                                          const int* __restrict__ csr_src,
                                          float* __restrict__ mOut,
                                          float* __restrict__ zInvOut, int N) {
  int wid = (blockIdx.x * blockDim.x + threadIdx.x) >> 6;
  int lane = threadIdx.x & 63;
  if (wid >= N) return;
  int h1 = lane & 3, slot = lane >> 2;
  int beg = off[wid], cnt = off[wid + 1] - beg;
  float ad_h1 = a_d[wid * 4 + h1];
  float m = lrelu(a_s[wid * 4 + h1] + ad_h1);  // self logit seeds running max
  float z = (slot == 0) ? 1.f : 0.f;           // self contributes exp(0)=1
  for (int c0 = 0; c0 < cnt; c0 += 16) {
    int i = c0 + slot;
    int sv = (i < cnt) ? csr_src[beg + i] : 0;
    float l = (i < cnt) ? lrelu(a_s[(long)sv * 4 + h1] + ad_h1) : -1e30f;
    float lm = l;
    lm = fmaxf(lm, __shfl_xor(lm, 4));
    lm = fmaxf(lm, __shfl_xor(lm, 8));
    lm = fmaxf(lm, __shfl_xor(lm, 16));
    lm = fmaxf(lm, __shfl_xor(lm, 32));
    float m_new = fmaxf(m, lm);
    z *= __expf(m - m_new);
    z += (i < cnt) ? __expf(l - m_new) : 0.f;
    m = m_new;
  }
  z += __shfl_xor(z, 4);
  z += __shfl_xor(z, 8);
  z += __shfl_xor(z, 16);
  z += __shfl_xor(z, 32);
  if (slot == 0) {
    mOut[(long)h1 * N + wid] = m;
    zInvOut[(long)h1 * N + wid] = 1.f / (z + 1e-16f);
  }
}

// ---------------- phase B: XCD-sliced weighted aggregation ----------------
// slice = blockIdx & 7 -> round-robin dispatch pins slice s to XCD s, whose
// L2 then holds only the 3.2 MB h-slice [slice][*][32]. One wave per
// (node, slice); lane = slot*4 + colgrp (16 edge slots x 4 col groups of 8).
__launch_bounds__(256)
__global__ void gat_aggregate_slice_kernel(const _Float16* __restrict__ hblk,
                                           const float* __restrict__ a_s,
                                           const float* __restrict__ a_d,
                                           const float* __restrict__ mArr,
                                           const float* __restrict__ zInv,
                                           const int* __restrict__ off,
                                           const int* __restrict__ csr_src,
                                           const float* __restrict__ bias,
                                           _Float16* __restrict__ outblk,
                                           int N, int Mp) {
  int bid = blockIdx.x;
  int slice = bid & 7;
  int wid = (bid >> 3) * 4 + (threadIdx.x >> 6);
  int lane = threadIdx.x & 63;
  if (wid >= N) return;
  int colg = lane & 3, slot = lane >> 2;
  int hb = slice >> 1;  // head = col>>6 = slice>>1
  const _Float16* hs = hblk + (long)slice * Mp * 32;
  int beg = off[wid], cnt = off[wid + 1] - beg;
  float m = mArr[(long)hb * N + wid];
  float inv = zInv[(long)hb * N + wid];
  float ad_hb = a_d[wid * 4 + hb];
  float acc[8] = {};
  if (slot == 0) {  // self-loop term
    float lself = lrelu(a_s[wid * 4 + hb] + ad_hb);
    float p = __expf(lself - m);
    half8v sr = *(const half8v*)(hs + (long)wid * 32 + colg * 8);
#pragma unroll
    for (int j = 0; j < 8; ++j) acc[j] = p * (float)sr[j];
  }
  for (int c0 = 0; c0 < cnt; c0 += 16) {
    int i = c0 + slot;
    if (i < cnt) {
      int sv = csr_src[beg + i];
      float l = lrelu(a_s[(long)sv * 4 + hb] + ad_hb);
      float p = __expf(l - m);
      half8v rv = *(const half8v*)(hs + (long)sv * 32 + colg * 8);
#pragma unroll
      for (int j = 0; j < 8; ++j) acc[j] = fmaf(p, (float)rv[j], acc[j]);
    }
  }
#pragma unroll
  for (int j = 0; j < 8; ++j) {
    acc[j] += __shfl_xor(acc[j], 4);
    acc[j] += __shfl_xor(acc[j], 8);
    acc[j] += __shfl_xor(acc[j], 16);
    acc[j] += __shfl_xor(acc[j], 32);
  }
  if (slot == 0) {
    int cbase = slice * 32 + colg * 8;
    half8v o;
#pragma unroll
    for (int j = 0; j < 8; ++j) o[j] = (_Float16)elu1(fmaf(acc[j], inv, bias[cbase + j]));
    *(half8v*)(outblk + (long)slice * Mp * 32 + (long)wid * 32 + colg * 8) = o;
  }
}

// ---------------------------------------------------------------------------
static inline int cdiv(int a, int b) { return (a + b - 1) / b; }

extern "C" void kernel_launch(void* const* d_in, const int* in_sizes, int n_in,
                              void* d_out, int out_size, void* d_ws, size_t ws_size,
                              hipStream_t stream) {
  const float* x = (const float*)d_in[0];
  const int* ei = (const int*)d_in[1];
  const float* W1 = (const float*)d_in[2];
  const float* as1 = (const float*)d_in[3];
  const float* ad1 = (const float*)d_in[4];
  const float* b1 = (const float*)d_in[5];
  const float* W2 = (const float*)d_in[6];
  const float* as2 = (const float*)d_in[7];
  const float* ad2 = (const float*)d_in[8];
  const float* b2 = (const float*)d_in[9];
  const float* lw1 = (const float*)d_in[10];
  const float* lb1 = (const float*)d_in[11];
  const float* lw2 = (const float*)d_in[12];
  const float* lb2 = (const float*)d_in[13];
  float* out = (float*)d_out;

  int N = in_sizes[0] / 128;  // 50000
  int E = in_sizes[1] / 2;    // 800000
  int Mp = cdiv(N, 64) * 64;  // 50048

  char* ws = (char*)d_ws;
  _Float16* Wt1 = (_Float16*)ws; ws += 256 * 128 * 2;
  _Float16* Wt2 = (_Float16*)ws; ws += 256 * 256 * 2;
  _Float16* WL = (_Float16*)ws; ws += 64 * 256 * 2;
  _Float16* C = (_Float16*)ws; ws += (size_t)Mp * 256 * 2;   // GEMM out (blocked)
  _Float16* h2 = (_Float16*)ws; ws += (size_t)Mp * 256 * 2;  // aggregate out (blocked)
  float* aS = (float*)ws; ws += (size_t)N * 4 * 4;
  float* aD = (float*)ws; ws += (size_t)N * 4 * 4;
  float* mArr = (float*)ws; ws += (size_t)N * 4 * 4;
  float* zInv = (float*)ws; ws += (size_t)N * 4 * 4;
  int* csr_src = (int*)ws; ws += (size_t)E * 4;
  int* indeg = (int*)ws; ws += (size_t)N * 4;
  int* cursor = (int*)ws; ws += (size_t)N * 4;
  int* off = (int*)ws; ws += (size_t)(N + 4) * 4;
  int* incl = (int*)ws; ws += (size_t)N * 4;
  int* bsum = (int*)ws; ws += 64 * 4;

  const int* e_src = ei;
  const int* e_dst = ei + E;
  int nb = cdiv(N, 1024);

  // weight conversion + indeg zeroing (one launch)
  convert_weights_kernel<<<cdiv(114688 + N, 256), 256, 0, stream>>>(W1, W2, lw1, Wt1, Wt2, WL,
                                                                    indeg, N);

  // CSR build
  count_kernel<<<cdiv(E, 256), 256, 0, stream>>>(e_dst, E, indeg);
  scan_block_kernel<<<nb, 1024, 0, stream>>>(indeg, incl, bsum, N);
  scan_finalize_kernel<<<cdiv(N, 256), 256, 0, stream>>>(indeg, incl, bsum, off, cursor, N);
  fill_kernel<<<cdiv(E, 256), 256, 0, stream>>>(e_src, e_dst, E, cursor, csr_src);

  // Layer 1
  mfma_gemm_attn_kernel<float><<<dim3(2, Mp / 64), 256, 0, stream>>>(x, Wt1, as1, ad1, C, aS, aD,
                                                                     N, 128, Mp);
  attn_softmax_stats_kernel<<<cdiv(N, 4), 256, 0, stream>>>(aS, aD, off, csr_src, mArr, zInv, N);
  gat_aggregate_slice_kernel<<<8 * cdiv(N, 4), 256, 0, stream>>>(C, aS, aD, mArr, zInv, off,
                                                                 csr_src, b1, h2, N, Mp);

  // Layer 2
  mfma_gemm_attn_kernel<_Float16><<<dim3(2, Mp / 64), 256, 0, stream>>>(h2, Wt2, as2, ad2, C, aS,
                                                                        aD, N, 256, Mp);
  attn_softmax_stats_kernel<<<cdiv(N, 4), 256, 0, stream>>>(aS, aD, off, csr_src, mArr, zInv, N);
  gat_aggregate_slice_kernel<<<8 * cdiv(N, 4), 256, 0, stream>>>(C, aS, aD, mArr, zInv, off,
                                                                 csr_src, b2, h2, N, Mp);

  // Head (MFMA, fused epilogue)
  head_mfma_kernel<<<Mp / 64, 256, 0, stream>>>(h2, WL, lb1, lw2, lb2, out, N, Mp);
}

// Round 2
// 407.061 us; speedup vs baseline: 1.4118x; 1.4118x over previous
//
#include <hip/hip_runtime.h>
#include <math.h>

// ---------------------------------------------------------------------------
// GAT IoT classifier — round 23: precomputed-alpha aggregation.
// r22 post-mortem: XCD column-slicing cut FETCH 208.8->76.4 MB (theory right
// on traffic) but 8x-replicated the per-wave overhead (avg degree 16 -> ~1
// loop iter/wave; 400k waves x ~100 VALU insts) -> 67->172 us. Reverted.
// This round keeps r19's single-pass full-row aggregate but hoists the
// per-edge softmax out: stats kernel (proved ~free in r22) now also writes
// per-(edge,head) alpha = exp(l - m) (fp32, coalesced). Aggregate inner loop
// is now shfl(sv) -> alpha load -> 16B h gather -> 8 FMA: no dependent a_s
// gather, no 4-deep shfl max-reduce, no online rescale -> better MLP on the
// compulsory 8-XCD 205 MB sweep, ~half the VALU.
// Predicted: aggregate 67 -> ~50 us each, VALUBusy 44 -> ~25%.
// ---------------------------------------------------------------------------

typedef __attribute__((ext_vector_type(8))) _Float16 half8v;  // 8 fp16 (4 VGPRs)
typedef __attribute__((ext_vector_type(4))) float f32x4;

__device__ __forceinline__ float lrelu(float x) { return x > 0.f ? x : 0.2f * x; }
__device__ __forceinline__ float elu1(float x) { return x > 0.f ? x : (__expf(x) - 1.f); }

// ---------------- weights -> transposed fp16 + indeg zeroing, one launch ------
__global__ void convert_weights_kernel(const float* __restrict__ W1, const float* __restrict__ W2,
                                       const float* __restrict__ lw1,
                                       _Float16* __restrict__ o1, _Float16* __restrict__ o2,
                                       _Float16* __restrict__ o3, int* __restrict__ indeg,
                                       int N) {
  int t = blockIdx.x * blockDim.x + threadIdx.x;
  if (t < 32768) {                       // W1
    int n = t >> 7, k = t & 127;
    o1[t] = (_Float16)W1[(long)k * 256 + n];
  } else if (t < 98304) {                // W2
    int i = t - 32768;
    int n = i >> 8, k = i & 255;
    o2[i] = (_Float16)W2[(long)k * 256 + n];
  } else if (t < 114688) {               // lw1
    int i = t - 98304;
    int n = i >> 8, k = i & 255;
    o3[i] = (_Float16)lw1[(long)k * 64 + n];
  } else if (t < 114688 + N) {           // indeg zeroing
    indeg[t - 114688] = 0;
  }
}

// ---------------- CSR build ----------------
__global__ void count_kernel(const int* __restrict__ dst, int E, int* __restrict__ indeg) {
  int e = blockIdx.x * blockDim.x + threadIdx.x;
  if (e < E) atomicAdd(&indeg[dst[e]], 1);
}

__global__ void scan_block_kernel(const int* __restrict__ in, int* __restrict__ incl,
                                  int* __restrict__ bsum, int N) {
  __shared__ int wsum[16];
  int gid = blockIdx.x * 1024 + threadIdx.x;
  int lane = threadIdx.x & 63, w = threadIdx.x >> 6;
  int v = (gid < N) ? in[gid] : 0;
  int sv = v;
#pragma unroll
  for (int o = 1; o < 64; o <<= 1) {
    int t = __shfl_up(sv, o);
    if (lane >= o) sv += t;
  }
  if (lane == 63) wsum[w] = sv;
  __syncthreads();
  if (w == 0) {
    int bs = (lane < 16) ? wsum[lane] : 0;
#pragma unroll
    for (int o = 1; o < 16; o <<= 1) {
      int t = __shfl_up(bs, o);
      if (lane >= o) bs += t;
    }
    if (lane < 16) wsum[lane] = bs;
  }
  __syncthreads();
  if (w > 0) sv += wsum[w - 1];
  if (gid < N) incl[gid] = sv;
  if (threadIdx.x == 1023) bsum[blockIdx.x] = sv;
}

__global__ void scan_finalize_kernel(const int* __restrict__ in, const int* __restrict__ incl,
                                     const int* __restrict__ bsum, int* __restrict__ off,
                                     int* __restrict__ cursor, int N) {
  int gid = blockIdx.x * blockDim.x + threadIdx.x;
  if (gid >= N) return;
  int b = gid >> 10;
  int carry = 0;
  for (int k = 0; k < b; ++k) carry += bsum[k];
  int ic = incl[gid] + carry;
  off[gid + 1] = ic;
  cursor[gid] = ic - in[gid];
  if (gid == 0) off[0] = 0;
}

__global__ void fill_kernel(const int* __restrict__ src, const int* __restrict__ dst, int E,
                            int* __restrict__ cursor, int* __restrict__ csr_src) {
  int e = blockIdx.x * blockDim.x + threadIdx.x;
  if (e < E) {
    int pos = atomicAdd(&cursor[dst[e]], 1);
    csr_src[pos] = src[e];
  }
}

// ---------------- fp16 MFMA GEMM (2 head blocks/block) + attn epilogue ----
// C[M,256] = A[M,K] x W[K,256]; W transposed [256][K]. Row-major C (r19).
template <typename AT>
__launch_bounds__(256)
__global__ void mfma_gemm_attn_kernel(const AT* __restrict__ A,
                                      const _Float16* __restrict__ B,
                                      const float* __restrict__ att_s,
                                      const float* __restrict__ att_d,
                                      _Float16* __restrict__ C,
                                      float* __restrict__ a_s, float* __restrict__ a_d,
                                      int M, int K) {
  __shared__ _Float16 As[64][40];     // 10.2+5.1 KB total: residency-safe
  __shared__ _Float16 Bs[2][64][40];
  int tid = threadIdx.x;
  int bm = blockIdx.y * 64, bn = blockIdx.x * 128;
  int lane = tid & 63, wave = tid >> 6;
  int srow = tid >> 2, sch = (tid & 3) * 8;
  const AT* Ap = A + (long)(bm + srow) * K + sch;
  const _Float16* Bp0 = B + (long)(bn + srow) * K + sch;
  const _Float16* Bp1 = B + (long)(bn + 64 + srow) * K + sch;
  bool arow_ok = (bm + srow) < M;
  int fm = lane & 15, fq = lane >> 4;
  f32x4 acc[2][4];
#pragma unroll
  for (int t = 0; t < 2; ++t)
#pragma unroll
    for (int cb = 0; cb < 4; ++cb) acc[t][cb] = (f32x4){0.f, 0.f, 0.f, 0.f};
  for (int k0 = 0; k0 < K; k0 += 32) {
    half8v a8 = {0, 0, 0, 0, 0, 0, 0, 0};
    if (arow_ok) {
      if constexpr (sizeof(AT) == 4) {
        float4 f0 = *(const float4*)(Ap + k0);
        float4 f1 = *(const float4*)(Ap + k0 + 4);
        a8 = (half8v){(_Float16)f0.x, (_Float16)f0.y, (_Float16)f0.z, (_Float16)f0.w,
                      (_Float16)f1.x, (_Float16)f1.y, (_Float16)f1.z, (_Float16)f1.w};
      } else {
        a8 = *(const half8v*)(Ap + k0);
      }
    }
    uint4 vb0 = *(const uint4*)(Bp0 + k0);
    uint4 vb1 = *(const uint4*)(Bp1 + k0);
    *(half8v*)&As[srow][sch] = a8;
    *(uint4*)&Bs[0][srow][sch] = vb0;
    *(uint4*)&Bs[1][srow][sch] = vb1;
    __syncthreads();
    half8v ah = *(const half8v*)&As[wave * 16 + fm][fq * 8];
#pragma unroll
    for (int t = 0; t < 2; ++t)
#pragma unroll
      for (int cb = 0; cb < 4; ++cb) {
        half8v bh = *(const half8v*)&Bs[t][cb * 16 + fm][fq * 8];
        acc[t][cb] = __builtin_amdgcn_mfma_f32_16x16x32_f16(ah, bh, acc[t][cb], 0, 0, 0);
      }
    __syncthreads();
  }
  int row0 = bm + wave * 16 + fq * 4;
#pragma unroll
  for (int t = 0; t < 2; ++t) {
    int headi = blockIdx.x * 2 + t;
    int cbase = bn + t * 64;
    float asv[4], adv[4];
#pragma unroll
    for (int cb = 0; cb < 4; ++cb) {
      int col = cbase + cb * 16 + fm;
      asv[cb] = att_s[col];
      adv[cb] = att_d[col];
    }
#pragma unroll
    for (int r = 0; r < 4; ++r) {
      int row = row0 + r;
      float sp = 0.f, dp = 0.f;
#pragma unroll
      for (int cb = 0; cb < 4; ++cb) {
        float v = acc[t][cb][r];
        sp = fmaf(v, asv[cb], sp);
        dp = fmaf(v, adv[cb], dp);
        if (row < M) C[(long)row * 256 + cbase + cb * 16 + fm] = (_Float16)v;
      }
#pragma unroll
      for (int o = 1; o < 16; o <<= 1) {
        sp += __shfl_xor(sp, o);
        dp += __shfl_xor(dp, o);
      }
      if (fm == 0 && row < M) {
        a_s[(long)row * 4 + headi] = sp;
        a_d[(long)row * 4 + headi] = dp;
      }
    }
  }
}

// ---------------- fused fp16 MFMA head ----------------
__launch_bounds__(256)
__global__ void head_mfma_kernel(const _Float16* __restrict__ A, const _Float16* __restrict__ B,
                                 const float* __restrict__ lb1, const float* __restrict__ lw2,
                                 const float* __restrict__ lb2, float* __restrict__ out, int M) {
  __shared__ _Float16 As[64][40];
  __shared__ _Float16 Bs[64][40];
  int tid = threadIdx.x;
  int bm = blockIdx.x * 64;
  int lane = tid & 63, wave = tid >> 6;
  int srow = tid >> 2, sch = (tid & 3) * 8;
  const _Float16* Ap = A + (long)(bm + srow) * 256 + sch;
  const _Float16* Bp = B + (long)srow * 256 + sch;
  int fm = lane & 15, fq = lane >> 4;
  f32x4 acc[4];
#pragma unroll
  for (int cb = 0; cb < 4; ++cb) acc[cb] = (f32x4){0.f, 0.f, 0.f, 0.f};
  for (int k0 = 0; k0 < 256; k0 += 32) {
    uint4 va = *(const uint4*)(Ap + k0);
    uint4 vb = *(const uint4*)(Bp + k0);
    *(uint4*)&As[srow][sch] = va;
    *(uint4*)&Bs[srow][sch] = vb;
    __syncthreads();
    half8v ah = *(const half8v*)&As[wave * 16 + fm][fq * 8];
#pragma unroll
    for (int cb = 0; cb < 4; ++cb) {
      half8v bh = *(const half8v*)&Bs[cb * 16 + fm][fq * 8];
      acc[cb] = __builtin_amdgcn_mfma_f32_16x16x32_f16(ah, bh, acc[cb], 0, 0, 0);
    }
    __syncthreads();
  }
  float lb1c[4], w20[4], w21[4];
#pragma unroll
  for (int cb = 0; cb < 4; ++cb) {
    int col = cb * 16 + fm;
    lb1c[cb] = lb1[col];
    w20[cb] = lw2[col * 2 + 0];
    w21[cb] = lw2[col * 2 + 1];
  }
  float b20 = lb2[0], b21 = lb2[1];
#pragma unroll
  for (int r = 0; r < 4; ++r) {
    float v0 = 0.f, v1 = 0.f;
#pragma unroll
    for (int cb = 0; cb < 4; ++cb) {
      float s = fmaxf(acc[cb][r] + lb1c[cb], 0.f);
      v0 = fmaf(s, w20[cb], v0);
      v1 = fmaf(s, w21[cb], v1);
    }
#pragma unroll
    for (int o = 1; o < 16; o <<= 1) {
      v0 += __shfl_xor(v0, o);
      v1 += __shfl_xor(v1, o);
    }
    if (fm == 0) {
      int row = bm + wave * 16 + fq * 4 + r;
      if (row < M) {
        v0 += b20;
        v1 += b21;
        float mx = fmaxf(v0, v1);
        float ls = mx + logf(expf(v0 - mx) + expf(v1 - mx));
        out[(long)row * 2 + 0] = v0 - ls;
        out[(long)row * 2 + 1] = v1 - ls;
      }
    }
  }
}

// ---------------- per-node softmax stats + per-edge alpha precompute -------
// One wave per node, lane = slot*4 + head. Pass 1: online m,z (r22-proven).
// Pass 2: alpha[e][h] = exp(l - m), written fully coalesced (256 B/iter).
// a_s table is 800 KB -> gathers are L2-hot; pass 2 re-gathers L1/L2-warm.
__launch_bounds__(256)
__global__ void attn_softmax_stats_kernel(const float* __restrict__ a_s,
                                          const float* __restrict__ a_d,
                                          const int* __restrict__ off,
                                          const int* __restrict__ csr_src,
                                          float* __restrict__ mOut,
                                          float* __restrict__ zInvOut,
                                          float* __restrict__ alphaE, int N) {
  int wid = (blockIdx.x * blockDim.x + threadIdx.x) >> 6;
  int lane = threadIdx.x & 63;
  if (wid >= N) return;
  int h1 = lane & 3, slot = lane >> 2;
  int beg = off[wid], cnt = off[wid + 1] - beg;
  float ad_h1 = a_d[wid * 4 + h1];
  float m = lrelu(a_s[wid * 4 + h1] + ad_h1);  // self logit seeds running max
  float z = (slot == 0) ? 1.f : 0.f;           // self contributes exp(0)=1
  for (int c0 = 0; c0 < cnt; c0 += 16) {
    int i = c0 + slot;
    int sv = (i < cnt) ? csr_src[beg + i] : 0;
    float l = (i < cnt) ? lrelu(a_s[(long)sv * 4 + h1] + ad_h1) : -1e30f;
    float lm = l;
    lm = fmaxf(lm, __shfl_xor(lm, 4));
    lm = fmaxf(lm, __shfl_xor(lm, 8));
    lm = fmaxf(lm, __shfl_xor(lm, 16));
    lm = fmaxf(lm, __shfl_xor(lm, 32));
    float m_new = fmaxf(m, lm);
    z *= __expf(m - m_new);
    z += (i < cnt) ? __expf(l - m_new) : 0.f;
    m = m_new;
  }
  z += __shfl_xor(z, 4);
  z += __shfl_xor(z, 8);
  z += __shfl_xor(z, 16);
  z += __shfl_xor(z, 32);
  if (slot == 0) {
    mOut[(long)wid * 4 + h1] = m;
    zInvOut[(long)wid * 4 + h1] = 1.f / (z + 1e-16f);
  }
  // pass 2: per-edge alpha (coalesced: addr = (beg+c0)*4 + lane)
  for (int c0 = 0; c0 < cnt; c0 += 16) {
    int i = c0 + slot;
    if (i < cnt) {
      int sv = csr_src[beg + i];
      float l = lrelu(a_s[(long)sv * 4 + h1] + ad_h1);
      alphaE[(long)(beg + i) * 4 + h1] = __expf(l - m);
    }
  }
}

// ---------------- per-node aggregation, precomputed alpha ------------------
// One wave per node. lane: c = lane&31 (col group, c*8..c*8+7), hlf = lane>>5
// (2 edges in flight). Inner loop: shfl(sv) -> alpha load -> 16B gather ->
// 8 FMA. No a_s gather, no max-reduce, no online rescale.
__launch_bounds__(256)
__global__ void gat_aggregate_pre_kernel(const _Float16* __restrict__ h,
                                         const float* __restrict__ alphaE,
                                         const float* __restrict__ a_s,
                                         const float* __restrict__ a_d,
                                         const float* __restrict__ mArr,
                                         const float* __restrict__ zInv,
                                         const int* __restrict__ off,
                                         const int* __restrict__ csr_src,
                                         const float* __restrict__ bias,
                                         _Float16* __restrict__ outp, int N) {
  int wid = (blockIdx.x * blockDim.x + threadIdx.x) >> 6;
  int lane = threadIdx.x & 63;
  if (wid >= N) return;
  int c = lane & 31, hlf = lane >> 5, head4 = c >> 3;
  int beg = off[wid], cnt = off[wid + 1] - beg;
  float m = mArr[(long)wid * 4 + head4];
  float inv = zInv[(long)wid * 4 + head4];
  float acc[8] = {};
  if (hlf == 0) {  // self-loop term
    float pself = __expf(lrelu(a_s[(long)wid * 4 + head4] + a_d[(long)wid * 4 + head4]) - m);
    half8v sr = *(const half8v*)(h + (long)wid * 256 + c * 8);
#pragma unroll
    for (int i = 0; i < 8; ++i) acc[i] = pself * (float)sr[i];
  }
  const float* ap = alphaE + (long)beg * 4;
  for (int c0 = 0; c0 < cnt; c0 += 16) {
    int i2 = c0 + (lane & 15);
    int sv = (i2 < cnt) ? csr_src[beg + i2] : 0;
#pragma unroll 4
    for (int j = 0; j < 16; j += 2) {
      if (c0 + j >= cnt) break;
      int e = j + hlf;
      int s = __shfl(sv, e);
      float p = (c0 + e < cnt) ? ap[(long)(c0 + e) * 4 + head4] : 0.f;
      half8v rv = *(const half8v*)(h + (long)s * 256 + c * 8);
      acc[0] = fmaf(p, (float)rv[0], acc[0]);
      acc[1] = fmaf(p, (float)rv[1], acc[1]);
      acc[2] = fmaf(p, (float)rv[2], acc[2]);
      acc[3] = fmaf(p, (float)rv[3], acc[3]);
      acc[4] = fmaf(p, (float)rv[4], acc[4]);
      acc[5] = fmaf(p, (float)rv[5], acc[5]);
      acc[6] = fmaf(p, (float)rv[6], acc[6]);
      acc[7] = fmaf(p, (float)rv[7], acc[7]);
    }
  }
#pragma unroll
  for (int i = 0; i < 8; ++i) acc[i] += __shfl_xor(acc[i], 32);
  if (hlf == 0) {
    half8v o;
#pragma unroll
    for (int i = 0; i < 8; ++i) o[i] = (_Float16)elu1(fmaf(acc[i], inv, bias[c * 8 + i]));
    *(half8v*)(outp + (long)wid * 256 + c * 8) = o;
  }
}

// ---------------------------------------------------------------------------
static inline int cdiv(int a, int b) { return (a + b - 1) / b; }

extern "C" void kernel_launch(void* const* d_in, const int* in_sizes, int n_in,
                              void* d_out, int out_size, void* d_ws, size_t ws_size,
                              hipStream_t stream) {
  const float* x = (const float*)d_in[0];
  const int* ei = (const int*)d_in[1];
  const float* W1 = (const float*)d_in[2];
  const float* as1 = (const float*)d_in[3];
  const float* ad1 = (const float*)d_in[4];
  const float* b1 = (const float*)d_in[5];
  const float* W2 = (const float*)d_in[6];
  const float* as2 = (const float*)d_in[7];
  const float* ad2 = (const float*)d_in[8];
  const float* b2 = (const float*)d_in[9];
  const float* lw1 = (const float*)d_in[10];
  const float* lb1 = (const float*)d_in[11];
  const float* lw2 = (const float*)d_in[12];
  const float* lb2 = (const float*)d_in[13];
  float* out = (float*)d_out;

  int N = in_sizes[0] / 128;  // 50000
  int E = in_sizes[1] / 2;    // 800000
  int Mp = cdiv(N, 64) * 64;  // 50048

  char* ws = (char*)d_ws;
  _Float16* Wt1 = (_Float16*)ws; ws += 256 * 128 * 2;
  _Float16* Wt2 = (_Float16*)ws; ws += 256 * 256 * 2;
  _Float16* WL = (_Float16*)ws; ws += 64 * 256 * 2;
  _Float16* C = (_Float16*)ws; ws += (size_t)Mp * 256 * 2;   // GEMM out
  _Float16* h2 = (_Float16*)ws; ws += (size_t)Mp * 256 * 2;  // aggregate out
  float* aS = (float*)ws; ws += (size_t)N * 4 * 4;
  float* aD = (float*)ws; ws += (size_t)N * 4 * 4;
  float* mArr = (float*)ws; ws += (size_t)N * 4 * 4;
  float* zInv = (float*)ws; ws += (size_t)N * 4 * 4;
  float* alphaE = (float*)ws; ws += (size_t)E * 4 * 4;       // 12.8 MB
  int* csr_src = (int*)ws; ws += (size_t)E * 4;
  int* indeg = (int*)ws; ws += (size_t)N * 4;
  int* cursor = (int*)ws; ws += (size_t)N * 4;
  int* off = (int*)ws; ws += (size_t)(N + 4) * 4;
  int* incl = (int*)ws; ws += (size_t)N * 4;
  int* bsum = (int*)ws; ws += 64 * 4;

  const int* e_src = ei;
  const int* e_dst = ei + E;
  int nb = cdiv(N, 1024);

  // weight conversion + indeg zeroing (one launch)
  convert_weights_kernel<<<cdiv(114688 + N, 256), 256, 0, stream>>>(W1, W2, lw1, Wt1, Wt2, WL,
                                                                    indeg, N);

  // CSR build
  count_kernel<<<cdiv(E, 256), 256, 0, stream>>>(e_dst, E, indeg);
  scan_block_kernel<<<nb, 1024, 0, stream>>>(indeg, incl, bsum, N);
  scan_finalize_kernel<<<cdiv(N, 256), 256, 0, stream>>>(indeg, incl, bsum, off, cursor, N);
  fill_kernel<<<cdiv(E, 256), 256, 0, stream>>>(e_src, e_dst, E, cursor, csr_src);

  // Layer 1
  mfma_gemm_attn_kernel<float><<<dim3(2, Mp / 64), 256, 0, stream>>>(x, Wt1, as1, ad1, C, aS, aD,
                                                                     N, 128);
  attn_softmax_stats_kernel<<<cdiv(N, 4), 256, 0, stream>>>(aS, aD, off, csr_src, mArr, zInv,
                                                            alphaE, N);
  gat_aggregate_pre_kernel<<<cdiv(N, 4), 256, 0, stream>>>(C, alphaE, aS, aD, mArr, zInv, off,
                                                           csr_src, b1, h2, N);

  // Layer 2
  mfma_gemm_attn_kernel<_Float16><<<dim3(2, Mp / 64), 256, 0, stream>>>(h2, Wt2, as2, ad2, C, aS,
                                                                        aD, N, 256);
  attn_softmax_stats_kernel<<<cdiv(N, 4), 256, 0, stream>>>(aS, aD, off, csr_src, mArr, zInv,
                                                            alphaE, N);
  gat_aggregate_pre_kernel<<<cdiv(N, 4), 256, 0, stream>>>(C, alphaE, aS, aD, mArr, zInv, off,
                                                           csr_src, b2, h2, N);

  // Head (MFMA, fused epilogue)
  head_mfma_kernel<<<Mp / 64, 256, 0, stream>>>(h2, WL, lb1, lw2, lb2, out, N);
}

// Round 3
// 380.877 us; speedup vs baseline: 1.5089x; 1.0687x over previous
//
#include <hip/hip_runtime.h>
#include <math.h>

// ---------------------------------------------------------------------------
// GAT IoT classifier — round 24: no-max softmax + deep-MLP aggregate.
// r23 post-mortem: precomputed alpha cut aggregate only 67->63.9 us (VALU
// wasn't the critical path) and the extra stats pass cost ~50 us -> net
// regression. Aggregate is latency/MLP-bound (3.58 TB/s, 45% peak, VALU 39%).
// r24: (a) alpha = exp(l) directly -- logits sigma~1.3, max ~7, fp32-safe;
// max-reduce, online rescale, and stats kernel all deleted; exact same e/z
// ratios as reference (m cancels). (b) inner loop restructured: all 8 h-row
// gathers issued into registers before the logit/exp chain -> 8 outstanding
// 16B gathers/wave on the compulsory 8-XCD sweep.
// Predicted: aggregate 67 -> ~50-57 us, hbm ~4.5 TB/s; total ~330-342 us.
// ---------------------------------------------------------------------------

typedef __attribute__((ext_vector_type(8))) _Float16 half8v;  // 8 fp16 (4 VGPRs)
typedef __attribute__((ext_vector_type(4))) float f32x4;

__device__ __forceinline__ float lrelu(float x) { return x > 0.f ? x : 0.2f * x; }
__device__ __forceinline__ float elu1(float x) { return x > 0.f ? x : (__expf(x) - 1.f); }

// ---------------- weights -> transposed fp16 + indeg zeroing, one launch ------
__global__ void convert_weights_kernel(const float* __restrict__ W1, const float* __restrict__ W2,
                                       const float* __restrict__ lw1,
                                       _Float16* __restrict__ o1, _Float16* __restrict__ o2,
                                       _Float16* __restrict__ o3, int* __restrict__ indeg,
                                       int N) {
  int t = blockIdx.x * blockDim.x + threadIdx.x;
  if (t < 32768) {                       // W1
    int n = t >> 7, k = t & 127;
    o1[t] = (_Float16)W1[(long)k * 256 + n];
  } else if (t < 98304) {                // W2
    int i = t - 32768;
    int n = i >> 8, k = i & 255;
    o2[i] = (_Float16)W2[(long)k * 256 + n];
  } else if (t < 114688) {               // lw1
    int i = t - 98304;
    int n = i >> 8, k = i & 255;
    o3[i] = (_Float16)lw1[(long)k * 64 + n];
  } else if (t < 114688 + N) {           // indeg zeroing
    indeg[t - 114688] = 0;
  }
}

// ---------------- CSR build ----------------
__global__ void count_kernel(const int* __restrict__ dst, int E, int* __restrict__ indeg) {
  int e = blockIdx.x * blockDim.x + threadIdx.x;
  if (e < E) atomicAdd(&indeg[dst[e]], 1);
}

__global__ void scan_block_kernel(const int* __restrict__ in, int* __restrict__ incl,
                                  int* __restrict__ bsum, int N) {
  __shared__ int wsum[16];
  int gid = blockIdx.x * 1024 + threadIdx.x;
  int lane = threadIdx.x & 63, w = threadIdx.x >> 6;
  int v = (gid < N) ? in[gid] : 0;
  int sv = v;
#pragma unroll
  for (int o = 1; o < 64; o <<= 1) {
    int t = __shfl_up(sv, o);
    if (lane >= o) sv += t;
  }
  if (lane == 63) wsum[w] = sv;
  __syncthreads();
  if (w == 0) {
    int bs = (lane < 16) ? wsum[lane] : 0;
#pragma unroll
    for (int o = 1; o < 16; o <<= 1) {
      int t = __shfl_up(bs, o);
      if (lane >= o) bs += t;
    }
    if (lane < 16) wsum[lane] = bs;
  }
  __syncthreads();
  if (w > 0) sv += wsum[w - 1];
  if (gid < N) incl[gid] = sv;
  if (threadIdx.x == 1023) bsum[blockIdx.x] = sv;
}

__global__ void scan_finalize_kernel(const int* __restrict__ in, const int* __restrict__ incl,
                                     const int* __restrict__ bsum, int* __restrict__ off,
                                     int* __restrict__ cursor, int N) {
  int gid = blockIdx.x * blockDim.x + threadIdx.x;
  if (gid >= N) return;
  int b = gid >> 10;
  int carry = 0;
  for (int k = 0; k < b; ++k) carry += bsum[k];
  int ic = incl[gid] + carry;
  off[gid + 1] = ic;
  cursor[gid] = ic - in[gid];
  if (gid == 0) off[0] = 0;
}

__global__ void fill_kernel(const int* __restrict__ src, const int* __restrict__ dst, int E,
                            int* __restrict__ cursor, int* __restrict__ csr_src) {
  int e = blockIdx.x * blockDim.x + threadIdx.x;
  if (e < E) {
    int pos = atomicAdd(&cursor[dst[e]], 1);
    csr_src[pos] = src[e];
  }
}

// ---------------- fp16 MFMA GEMM (2 head blocks/block) + attn epilogue ----
// C[M,256] = A[M,K] x W[K,256]; W transposed [256][K]. Row-major C.
template <typename AT>
__launch_bounds__(256)
__global__ void mfma_gemm_attn_kernel(const AT* __restrict__ A,
                                      const _Float16* __restrict__ B,
                                      const float* __restrict__ att_s,
                                      const float* __restrict__ att_d,
                                      _Float16* __restrict__ C,
                                      float* __restrict__ a_s, float* __restrict__ a_d,
                                      int M, int K) {
  __shared__ _Float16 As[64][40];     // 10.2+5.1 KB total: residency-safe
  __shared__ _Float16 Bs[2][64][40];
  int tid = threadIdx.x;
  int bm = blockIdx.y * 64, bn = blockIdx.x * 128;
  int lane = tid & 63, wave = tid >> 6;
  int srow = tid >> 2, sch = (tid & 3) * 8;
  const AT* Ap = A + (long)(bm + srow) * K + sch;
  const _Float16* Bp0 = B + (long)(bn + srow) * K + sch;
  const _Float16* Bp1 = B + (long)(bn + 64 + srow) * K + sch;
  bool arow_ok = (bm + srow) < M;
  int fm = lane & 15, fq = lane >> 4;
  f32x4 acc[2][4];
#pragma unroll
  for (int t = 0; t < 2; ++t)
#pragma unroll
    for (int cb = 0; cb < 4; ++cb) acc[t][cb] = (f32x4){0.f, 0.f, 0.f, 0.f};
  for (int k0 = 0; k0 < K; k0 += 32) {
    half8v a8 = {0, 0, 0, 0, 0, 0, 0, 0};
    if (arow_ok) {
      if constexpr (sizeof(AT) == 4) {
        float4 f0 = *(const float4*)(Ap + k0);
        float4 f1 = *(const float4*)(Ap + k0 + 4);
        a8 = (half8v){(_Float16)f0.x, (_Float16)f0.y, (_Float16)f0.z, (_Float16)f0.w,
                      (_Float16)f1.x, (_Float16)f1.y, (_Float16)f1.z, (_Float16)f1.w};
      } else {
        a8 = *(const half8v*)(Ap + k0);
      }
    }
    uint4 vb0 = *(const uint4*)(Bp0 + k0);
    uint4 vb1 = *(const uint4*)(Bp1 + k0);
    *(half8v*)&As[srow][sch] = a8;
    *(uint4*)&Bs[0][srow][sch] = vb0;
    *(uint4*)&Bs[1][srow][sch] = vb1;
    __syncthreads();
    half8v ah = *(const half8v*)&As[wave * 16 + fm][fq * 8];
#pragma unroll
    for (int t = 0; t < 2; ++t)
#pragma unroll
      for (int cb = 0; cb < 4; ++cb) {
        half8v bh = *(const half8v*)&Bs[t][cb * 16 + fm][fq * 8];
        acc[t][cb] = __builtin_amdgcn_mfma_f32_16x16x32_f16(ah, bh, acc[t][cb], 0, 0, 0);
      }
    __syncthreads();
  }
  int row0 = bm + wave * 16 + fq * 4;
#pragma unroll
  for (int t = 0; t < 2; ++t) {
    int headi = blockIdx.x * 2 + t;
    int cbase = bn + t * 64;
    float asv[4], adv[4];
#pragma unroll
    for (int cb = 0; cb < 4; ++cb) {
      int col = cbase + cb * 16 + fm;
      asv[cb] = att_s[col];
      adv[cb] = att_d[col];
    }
#pragma unroll
    for (int r = 0; r < 4; ++r) {
      int row = row0 + r;
      float sp = 0.f, dp = 0.f;
#pragma unroll
      for (int cb = 0; cb < 4; ++cb) {
        float v = acc[t][cb][r];
        sp = fmaf(v, asv[cb], sp);
        dp = fmaf(v, adv[cb], dp);
        if (row < M) C[(long)row * 256 + cbase + cb * 16 + fm] = (_Float16)v;
      }
#pragma unroll
      for (int o = 1; o < 16; o <<= 1) {
        sp += __shfl_xor(sp, o);
        dp += __shfl_xor(dp, o);
      }
      if (fm == 0 && row < M) {
        a_s[(long)row * 4 + headi] = sp;
        a_d[(long)row * 4 + headi] = dp;
      }
    }
  }
}

// ---------------- fused fp16 MFMA head ----------------
__launch_bounds__(256)
__global__ void head_mfma_kernel(const _Float16* __restrict__ A, const _Float16* __restrict__ B,
                                 const float* __restrict__ lb1, const float* __restrict__ lw2,
                                 const float* __restrict__ lb2, float* __restrict__ out, int M) {
  __shared__ _Float16 As[64][40];
  __shared__ _Float16 Bs[64][40];
  int tid = threadIdx.x;
  int bm = blockIdx.x * 64;
  int lane = tid & 63, wave = tid >> 6;
  int srow = tid >> 2, sch = (tid & 3) * 8;
  const _Float16* Ap = A + (long)(bm + srow) * 256 + sch;
  const _Float16* Bp = B + (long)srow * 256 + sch;
  int fm = lane & 15, fq = lane >> 4;
  f32x4 acc[4];
#pragma unroll
  for (int cb = 0; cb < 4; ++cb) acc[cb] = (f32x4){0.f, 0.f, 0.f, 0.f};
  for (int k0 = 0; k0 < 256; k0 += 32) {
    uint4 va = *(const uint4*)(Ap + k0);
    uint4 vb = *(const uint4*)(Bp + k0);
    *(uint4*)&As[srow][sch] = va;
    *(uint4*)&Bs[srow][sch] = vb;
    __syncthreads();
    half8v ah = *(const half8v*)&As[wave * 16 + fm][fq * 8];
#pragma unroll
    for (int cb = 0; cb < 4; ++cb) {
      half8v bh = *(const half8v*)&Bs[cb * 16 + fm][fq * 8];
      acc[cb] = __builtin_amdgcn_mfma_f32_16x16x32_f16(ah, bh, acc[cb], 0, 0, 0);
    }
    __syncthreads();
  }
  float lb1c[4], w20[4], w21[4];
#pragma unroll
  for (int cb = 0; cb < 4; ++cb) {
    int col = cb * 16 + fm;
    lb1c[cb] = lb1[col];
    w20[cb] = lw2[col * 2 + 0];
    w21[cb] = lw2[col * 2 + 1];
  }
  float b20 = lb2[0], b21 = lb2[1];
#pragma unroll
  for (int r = 0; r < 4; ++r) {
    float v0 = 0.f, v1 = 0.f;
#pragma unroll
    for (int cb = 0; cb < 4; ++cb) {
      float s = fmaxf(acc[cb][r] + lb1c[cb], 0.f);
      v0 = fmaf(s, w20[cb], v0);
      v1 = fmaf(s, w21[cb], v1);
    }
#pragma unroll
    for (int o = 1; o < 16; o <<= 1) {
      v0 += __shfl_xor(v0, o);
      v1 += __shfl_xor(v1, o);
    }
    if (fm == 0) {
      int row = bm + wave * 16 + fq * 4 + r;
      if (row < M) {
        v0 += b20;
        v1 += b21;
        float mx = fmaxf(v0, v1);
        float ls = mx + logf(expf(v0 - mx) + expf(v1 - mx));
        out[(long)row * 2 + 0] = v0 - ls;
        out[(long)row * 2 + 1] = v1 - ls;
      }
    }
  }
}

// ---------------- per-node aggregation: alpha = exp(l), deep-MLP gathers ---
// One wave per node. lane: c = lane&31 (8-col group), hlf = lane>>5 (2 edge
// halves), head4 = c>>3; logit lanes: h1 = lane&3, sl1 = lane>>2 (16 edges x
// 4 heads). Full 16-edge blocks: all 8 h-row gathers issued before the
// logit/exp chain (independent); tail block guarded r19-style.
__launch_bounds__(256)
__global__ void gat_aggregate_exp_kernel(const _Float16* __restrict__ h,
                                         const float* __restrict__ a_s,
                                         const float* __restrict__ a_d,
                                         const int* __restrict__ off,
                                         const int* __restrict__ csr_src,
                                         const float* __restrict__ bias,
                                         _Float16* __restrict__ outp, int N) {
  int wid = (blockIdx.x * blockDim.x + threadIdx.x) >> 6;
  int lane = threadIdx.x & 63;
  if (wid >= N) return;
  int c = lane & 31, hlf = lane >> 5, head4 = c >> 3;
  int h1 = lane & 3, sl1 = lane >> 2;
  int beg = off[wid], cnt = off[wid + 1] - beg;
  float ad_h1 = a_d[wid * 4 + h1];
  // self-loop: lanes 0..3 (sl1==0) hold head h1=lane; broadcast per head4
  float psl = __expf(lrelu(a_s[wid * 4 + h1] + ad_h1));
  float pself = __shfl(psl, head4);
  float z = 0.f;
  float acc[8] = {};
  if (hlf == 0) {
    z = pself;
    half8v sr = *(const half8v*)(h + (long)wid * 256 + c * 8);
#pragma unroll
    for (int i = 0; i < 8; ++i) acc[i] = pself * (float)sr[i];
  }
  int nfull = cnt & ~15;
  for (int c0 = 0; c0 < nfull; c0 += 16) {
    int sv = csr_src[beg + c0 + (lane & 15)];
    // issue all 8 row gathers first (depend only on sv)
    half8v rv0, rv1, rv2, rv3, rv4, rv5, rv6, rv7;
    {
      int s0 = __shfl(sv, 0 + hlf);
      int s1 = __shfl(sv, 2 + hlf);
      int s2 = __shfl(sv, 4 + hlf);
      int s3 = __shfl(sv, 6 + hlf);
      int s4 = __shfl(sv, 8 + hlf);
      int s5 = __shfl(sv, 10 + hlf);
      int s6 = __shfl(sv, 12 + hlf);
      int s7 = __shfl(sv, 14 + hlf);
      rv0 = *(const half8v*)(h + (long)s0 * 256 + c * 8);
      rv1 = *(const half8v*)(h + (long)s1 * 256 + c * 8);
      rv2 = *(const half8v*)(h + (long)s2 * 256 + c * 8);
      rv3 = *(const half8v*)(h + (long)s3 * 256 + c * 8);
      rv4 = *(const half8v*)(h + (long)s4 * 256 + c * 8);
      rv5 = *(const half8v*)(h + (long)s5 * 256 + c * 8);
      rv6 = *(const half8v*)(h + (long)s6 * 256 + c * 8);
      rv7 = *(const half8v*)(h + (long)s7 * 256 + c * 8);
    }
    // logit chain in parallel with gathers
    int spi = __shfl(sv, sl1);
    float pv = __expf(lrelu(a_s[(long)spi * 4 + h1] + ad_h1));
#define AGG_STEP(J, RV)                                             \
    {                                                               \
      float p = __shfl(pv, (2 * (J) + hlf) * 4 + head4);            \
      z += p;                                                       \
      acc[0] = fmaf(p, (float)RV[0], acc[0]);                       \
      acc[1] = fmaf(p, (float)RV[1], acc[1]);                       \
      acc[2] = fmaf(p, (float)RV[2], acc[2]);                       \
      acc[3] = fmaf(p, (float)RV[3], acc[3]);                       \
      acc[4] = fmaf(p, (float)RV[4], acc[4]);                       \
      acc[5] = fmaf(p, (float)RV[5], acc[5]);                       \
      acc[6] = fmaf(p, (float)RV[6], acc[6]);                       \
      acc[7] = fmaf(p, (float)RV[7], acc[7]);                       \
    }
    AGG_STEP(0, rv0)
    AGG_STEP(1, rv1)
    AGG_STEP(2, rv2)
    AGG_STEP(3, rv3)
    AGG_STEP(4, rv4)
    AGG_STEP(5, rv5)
    AGG_STEP(6, rv6)
    AGG_STEP(7, rv7)
#undef AGG_STEP
  }
  if (nfull < cnt) {  // tail: < 16 edges
    int i2 = nfull + (lane & 15);
    int sv = (i2 < cnt) ? csr_src[beg + i2] : 0;
    int i1 = nfull + sl1;
    int spi = __shfl(sv, sl1);
    float pv = (i1 < cnt) ? __expf(lrelu(a_s[(long)spi * 4 + h1] + ad_h1)) : 0.f;
#pragma unroll 4
    for (int j = 0; j < 16; j += 2) {
      if (nfull + j >= cnt) break;
      int e = j + hlf;
      int s = __shfl(sv, e);
      float p = __shfl(pv, e * 4 + head4);
      z += p;
      half8v rv = *(const half8v*)(h + (long)s * 256 + c * 8);
      acc[0] = fmaf(p, (float)rv[0], acc[0]);
      acc[1] = fmaf(p, (float)rv[1], acc[1]);
      acc[2] = fmaf(p, (float)rv[2], acc[2]);
      acc[3] = fmaf(p, (float)rv[3], acc[3]);
      acc[4] = fmaf(p, (float)rv[4], acc[4]);
      acc[5] = fmaf(p, (float)rv[5], acc[5]);
      acc[6] = fmaf(p, (float)rv[6], acc[6]);
      acc[7] = fmaf(p, (float)rv[7], acc[7]);
    }
  }
  z += __shfl_xor(z, 32);
#pragma unroll
  for (int i = 0; i < 8; ++i) acc[i] += __shfl_xor(acc[i], 32);
  if (hlf == 0) {
    float inv = 1.f / z;  // z >= pself > 0
    half8v o;
#pragma unroll
    for (int i = 0; i < 8; ++i) o[i] = (_Float16)elu1(fmaf(acc[i], inv, bias[c * 8 + i]));
    *(half8v*)(outp + (long)wid * 256 + c * 8) = o;
  }
}

// ---------------------------------------------------------------------------
static inline int cdiv(int a, int b) { return (a + b - 1) / b; }

extern "C" void kernel_launch(void* const* d_in, const int* in_sizes, int n_in,
                              void* d_out, int out_size, void* d_ws, size_t ws_size,
                              hipStream_t stream) {
  const float* x = (const float*)d_in[0];
  const int* ei = (const int*)d_in[1];
  const float* W1 = (const float*)d_in[2];
  const float* as1 = (const float*)d_in[3];
  const float* ad1 = (const float*)d_in[4];
  const float* b1 = (const float*)d_in[5];
  const float* W2 = (const float*)d_in[6];
  const float* as2 = (const float*)d_in[7];
  const float* ad2 = (const float*)d_in[8];
  const float* b2 = (const float*)d_in[9];
  const float* lw1 = (const float*)d_in[10];
  const float* lb1 = (const float*)d_in[11];
  const float* lw2 = (const float*)d_in[12];
  const float* lb2 = (const float*)d_in[13];
  float* out = (float*)d_out;

  int N = in_sizes[0] / 128;  // 50000
  int E = in_sizes[1] / 2;    // 800000
  int Mp = cdiv(N, 64) * 64;  // 50048

  char* ws = (char*)d_ws;
  _Float16* Wt1 = (_Float16*)ws; ws += 256 * 128 * 2;
  _Float16* Wt2 = (_Float16*)ws; ws += 256 * 256 * 2;
  _Float16* WL = (_Float16*)ws; ws += 64 * 256 * 2;
  _Float16* C = (_Float16*)ws; ws += (size_t)Mp * 256 * 2;   // GEMM out
  _Float16* h2 = (_Float16*)ws; ws += (size_t)Mp * 256 * 2;  // aggregate out
  float* aS = (float*)ws; ws += (size_t)N * 4 * 4;
  float* aD = (float*)ws; ws += (size_t)N * 4 * 4;
  int* csr_src = (int*)ws; ws += (size_t)E * 4;
  int* indeg = (int*)ws; ws += (size_t)N * 4;
  int* cursor = (int*)ws; ws += (size_t)N * 4;
  int* off = (int*)ws; ws += (size_t)(N + 4) * 4;
  int* incl = (int*)ws; ws += (size_t)N * 4;
  int* bsum = (int*)ws; ws += 64 * 4;

  const int* e_src = ei;
  const int* e_dst = ei + E;
  int nb = cdiv(N, 1024);

  // weight conversion + indeg zeroing (one launch)
  convert_weights_kernel<<<cdiv(114688 + N, 256), 256, 0, stream>>>(W1, W2, lw1, Wt1, Wt2, WL,
                                                                    indeg, N);

  // CSR build
  count_kernel<<<cdiv(E, 256), 256, 0, stream>>>(e_dst, E, indeg);
  scan_block_kernel<<<nb, 1024, 0, stream>>>(indeg, incl, bsum, N);
  scan_finalize_kernel<<<cdiv(N, 256), 256, 0, stream>>>(indeg, incl, bsum, off, cursor, N);
  fill_kernel<<<cdiv(E, 256), 256, 0, stream>>>(e_src, e_dst, E, cursor, csr_src);

  // Layer 1
  mfma_gemm_attn_kernel<float><<<dim3(2, Mp / 64), 256, 0, stream>>>(x, Wt1, as1, ad1, C, aS, aD,
                                                                     N, 128);
  gat_aggregate_exp_kernel<<<cdiv(N, 4), 256, 0, stream>>>(C, aS, aD, off, csr_src, b1, h2, N);

  // Layer 2
  mfma_gemm_attn_kernel<_Float16><<<dim3(2, Mp / 64), 256, 0, stream>>>(h2, Wt2, as2, ad2, C, aS,
                                                                        aD, N, 256);
  gat_aggregate_exp_kernel<<<cdiv(N, 4), 256, 0, stream>>>(C, aS, aD, off, csr_src, b2, h2, N);

  // Head (MFMA, fused epilogue)
  head_mfma_kernel<<<Mp / 64, 256, 0, stream>>>(h2, WL, lb1, lw2, lb2, out, N);
}

// Round 4
// 380.085 us; speedup vs baseline: 1.5120x; 1.0021x over previous
//
#include <hip/hip_runtime.h>
#include <math.h>

// ---------------------------------------------------------------------------
// GAT IoT classifier — round 25: 128x128 MFMA GEMMs + no-max r19 aggregate.
// r24 post-mortem: 8-gather ILP hoist -> VGPR 64 -> occupancy 36% -> 75.6 us
// (TLP loss > ILP gain). Aggregate BW plateaus ~3.6 TB/s across 3 structures
// => near pattern-roofline; keep r19 28-VGPR shape, drop only the max-reduce
// (no-max exp verified in r24, absmax unchanged).
// Main experiment: GEMMs moved from 64-row tile (8 MFMA/barrier-pair) to
// 128x128 tile, 4 waves x (4x4 frags) = 16 MFMA + 8 ds_read_b128 per K-step
// (m92->m93 ladder step, +51% there). Head -> 128x64 tile. Attn epilogue
// stays fused: wave's 64-col panel == one head.
// Predicted: aggregate ~60-64 us; GEMMs ~15-30 us each; total ~280-310 us.
// ---------------------------------------------------------------------------

typedef __attribute__((ext_vector_type(8))) _Float16 half8v;  // 8 fp16 (4 VGPRs)
typedef __attribute__((ext_vector_type(4))) float f32x4;

__device__ __forceinline__ float lrelu(float x) { return x > 0.f ? x : 0.2f * x; }
__device__ __forceinline__ float elu1(float x) { return x > 0.f ? x : (__expf(x) - 1.f); }

// ---------------- weights -> transposed fp16 + indeg zeroing, one launch ------
__global__ void convert_weights_kernel(const float* __restrict__ W1, const float* __restrict__ W2,
                                       const float* __restrict__ lw1,
                                       _Float16* __restrict__ o1, _Float16* __restrict__ o2,
                                       _Float16* __restrict__ o3, int* __restrict__ indeg,
                                       int N) {
  int t = blockIdx.x * blockDim.x + threadIdx.x;
  if (t < 32768) {                       // W1
    int n = t >> 7, k = t & 127;
    o1[t] = (_Float16)W1[(long)k * 256 + n];
  } else if (t < 98304) {                // W2
    int i = t - 32768;
    int n = i >> 8, k = i & 255;
    o2[i] = (_Float16)W2[(long)k * 256 + n];
  } else if (t < 114688) {               // lw1
    int i = t - 98304;
    int n = i >> 8, k = i & 255;
    o3[i] = (_Float16)lw1[(long)k * 64 + n];
  } else if (t < 114688 + N) {           // indeg zeroing
    indeg[t - 114688] = 0;
  }
}

// ---------------- CSR build ----------------
__global__ void count_kernel(const int* __restrict__ dst, int E, int* __restrict__ indeg) {
  int e = blockIdx.x * blockDim.x + threadIdx.x;
  if (e < E) atomicAdd(&indeg[dst[e]], 1);
}

__global__ void scan_block_kernel(const int* __restrict__ in, int* __restrict__ incl,
                                  int* __restrict__ bsum, int N) {
  __shared__ int wsum[16];
  int gid = blockIdx.x * 1024 + threadIdx.x;
  int lane = threadIdx.x & 63, w = threadIdx.x >> 6;
  int v = (gid < N) ? in[gid] : 0;
  int sv = v;
#pragma unroll
  for (int o = 1; o < 64; o <<= 1) {
    int t = __shfl_up(sv, o);
    if (lane >= o) sv += t;
  }
  if (lane == 63) wsum[w] = sv;
  __syncthreads();
  if (w == 0) {
    int bs = (lane < 16) ? wsum[lane] : 0;
#pragma unroll
    for (int o = 1; o < 16; o <<= 1) {
      int t = __shfl_up(bs, o);
      if (lane >= o) bs += t;
    }
    if (lane < 16) wsum[lane] = bs;
  }
  __syncthreads();
  if (w > 0) sv += wsum[w - 1];
  if (gid < N) incl[gid] = sv;
  if (threadIdx.x == 1023) bsum[blockIdx.x] = sv;
}

__global__ void scan_finalize_kernel(const int* __restrict__ in, const int* __restrict__ incl,
                                     const int* __restrict__ bsum, int* __restrict__ off,
                                     int* __restrict__ cursor, int N) {
  int gid = blockIdx.x * blockDim.x + threadIdx.x;
  if (gid >= N) return;
  int b = gid >> 10;
  int carry = 0;
  for (int k = 0; k < b; ++k) carry += bsum[k];
  int ic = incl[gid] + carry;
  off[gid + 1] = ic;
  cursor[gid] = ic - in[gid];
  if (gid == 0) off[0] = 0;
}

__global__ void fill_kernel(const int* __restrict__ src, const int* __restrict__ dst, int E,
                            int* __restrict__ cursor, int* __restrict__ csr_src) {
  int e = blockIdx.x * blockDim.x + threadIdx.x;
  if (e < E) {
    int pos = atomicAdd(&cursor[dst[e]], 1);
    csr_src[pos] = src[e];
  }
}

// ---------------- fp16 MFMA GEMM, 128x128 tile + attn epilogue ----
// C[M,256] = A[M,K] x W[K,256]; W transposed [256][K]. 4 waves in 2x2 grid,
// each owns a 64x64 quadrant = 4x4 16x16 frags; 16 MFMA + 8 ds_read_b128
// per K-step. Wave's 64-col panel == one head -> attn dot stays wave-local.
template <typename AT>
__launch_bounds__(256)
__global__ void mfma_gemm_attn_kernel(const AT* __restrict__ A,
                                      const _Float16* __restrict__ B,
                                      const float* __restrict__ att_s,
                                      const float* __restrict__ att_d,
                                      _Float16* __restrict__ C,
                                      float* __restrict__ a_s, float* __restrict__ a_d,
                                      int M, int K) {
  __shared__ _Float16 As[128][40];   // 10.24 KB, 80B stride: 2-way-free banks
  __shared__ _Float16 Bs[128][40];
  int tid = threadIdx.x;
  int bm = blockIdx.y * 128, bn = blockIdx.x * 128;
  int lane = tid & 63, wave = tid >> 6;
  int srow = tid >> 2, sch = (tid & 3) * 8;     // 64 rows x 32 cols per issue
  const AT* Ap0 = A + (long)(bm + srow) * K + sch;
  const AT* Ap1 = A + (long)(bm + 64 + srow) * K + sch;
  const _Float16* Bp0 = B + (long)(bn + srow) * K + sch;
  const _Float16* Bp1 = B + (long)(bn + 64 + srow) * K + sch;
  bool aok0 = (bm + srow) < M, aok1 = (bm + 64 + srow) < M;
  int fm = lane & 15, fq = lane >> 4;
  int wr = wave >> 1, wc = wave & 1;            // 2x2 wave grid
  f32x4 acc[4][4];
#pragma unroll
  for (int mi = 0; mi < 4; ++mi)
#pragma unroll
    for (int ni = 0; ni < 4; ++ni) acc[mi][ni] = (f32x4){0.f, 0.f, 0.f, 0.f};
  for (int k0 = 0; k0 < K; k0 += 32) {
    half8v a80 = {0, 0, 0, 0, 0, 0, 0, 0}, a81 = {0, 0, 0, 0, 0, 0, 0, 0};
    if constexpr (sizeof(AT) == 4) {
      if (aok0) {
        float4 f0 = *(const float4*)(Ap0 + k0);
        float4 f1 = *(const float4*)(Ap0 + k0 + 4);
        a80 = (half8v){(_Float16)f0.x, (_Float16)f0.y, (_Float16)f0.z, (_Float16)f0.w,
                       (_Float16)f1.x, (_Float16)f1.y, (_Float16)f1.z, (_Float16)f1.w};
      }
      if (aok1) {
        float4 f0 = *(const float4*)(Ap1 + k0);
        float4 f1 = *(const float4*)(Ap1 + k0 + 4);
        a81 = (half8v){(_Float16)f0.x, (_Float16)f0.y, (_Float16)f0.z, (_Float16)f0.w,
                       (_Float16)f1.x, (_Float16)f1.y, (_Float16)f1.z, (_Float16)f1.w};
      }
    } else {
      if (aok0) a80 = *(const half8v*)(Ap0 + k0);
      if (aok1) a81 = *(const half8v*)(Ap1 + k0);
    }
    uint4 vb0 = *(const uint4*)(Bp0 + k0);
    uint4 vb1 = *(const uint4*)(Bp1 + k0);
    *(half8v*)&As[srow][sch] = a80;
    *(half8v*)&As[64 + srow][sch] = a81;
    *(uint4*)&Bs[srow][sch] = vb0;
    *(uint4*)&Bs[64 + srow][sch] = vb1;
    __syncthreads();
    half8v ah[4], bh[4];
#pragma unroll
    for (int i = 0; i < 4; ++i) ah[i] = *(const half8v*)&As[wr * 64 + i * 16 + fm][fq * 8];
#pragma unroll
    for (int i = 0; i < 4; ++i) bh[i] = *(const half8v*)&Bs[wc * 64 + i * 16 + fm][fq * 8];
#pragma unroll
    for (int mi = 0; mi < 4; ++mi)
#pragma unroll
      for (int ni = 0; ni < 4; ++ni)
        acc[mi][ni] = __builtin_amdgcn_mfma_f32_16x16x32_f16(ah[mi], bh[ni], acc[mi][ni], 0, 0, 0);
    __syncthreads();
  }
  // epilogue: C store + per-head attn dots (wave's 64 cols == head headi)
  int headi = blockIdx.x * 2 + wc;
  int cbase = bn + wc * 64;
  float asv[4], adv[4];
#pragma unroll
  for (int ni = 0; ni < 4; ++ni) {
    int col = cbase + ni * 16 + fm;
    asv[ni] = att_s[col];
    adv[ni] = att_d[col];
  }
#pragma unroll
  for (int mi = 0; mi < 4; ++mi) {
    int rowb = bm + wr * 64 + mi * 16 + fq * 4;
#pragma unroll
    for (int r = 0; r < 4; ++r) {
      int row = rowb + r;
      float sp = 0.f, dp = 0.f;
#pragma unroll
      for (int ni = 0; ni < 4; ++ni) {
        float v = acc[mi][ni][r];
        sp = fmaf(v, asv[ni], sp);
        dp = fmaf(v, adv[ni], dp);
        if (row < M) C[(long)row * 256 + cbase + ni * 16 + fm] = (_Float16)v;
      }
#pragma unroll
      for (int o = 1; o < 16; o <<= 1) {
        sp += __shfl_xor(sp, o);
        dp += __shfl_xor(dp, o);
      }
      if (fm == 0 && row < M) {
        a_s[(long)row * 4 + headi] = sp;
        a_d[(long)row * 4 + headi] = dp;
      }
    }
  }
}

// ---------------- fused fp16 MFMA head, 128x64 tile ----------------
__launch_bounds__(256)
__global__ void head_mfma_kernel(const _Float16* __restrict__ A, const _Float16* __restrict__ B,
                                 const float* __restrict__ lb1, const float* __restrict__ lw2,
                                 const float* __restrict__ lb2, float* __restrict__ out, int M) {
  __shared__ _Float16 As[128][40];
  __shared__ _Float16 Bs[64][40];
  int tid = threadIdx.x;
  int bm = blockIdx.x * 128;
  int lane = tid & 63, wave = tid >> 6;
  int srow = tid >> 2, sch = (tid & 3) * 8;
  const _Float16* Ap0 = A + (long)(bm + srow) * 256 + sch;
  const _Float16* Ap1 = A + (long)(bm + 64 + srow) * 256 + sch;
  const _Float16* Bp = B + (long)srow * 256 + sch;
  bool aok0 = (bm + srow) < M, aok1 = (bm + 64 + srow) < M;
  int fm = lane & 15, fq = lane >> 4;
  f32x4 acc[2][4];   // wave owns rows wave*32..+31: 2 m-frags x 4 n-frags
#pragma unroll
  for (int mi = 0; mi < 2; ++mi)
#pragma unroll
    for (int ni = 0; ni < 4; ++ni) acc[mi][ni] = (f32x4){0.f, 0.f, 0.f, 0.f};
  for (int k0 = 0; k0 < 256; k0 += 32) {
    half8v a80 = {0, 0, 0, 0, 0, 0, 0, 0}, a81 = {0, 0, 0, 0, 0, 0, 0, 0};
    if (aok0) a80 = *(const half8v*)(Ap0 + k0);
    if (aok1) a81 = *(const half8v*)(Ap1 + k0);
    uint4 vb = *(const uint4*)(Bp + k0);
    *(half8v*)&As[srow][sch] = a80;
    *(half8v*)&As[64 + srow][sch] = a81;
    *(uint4*)&Bs[srow][sch] = vb;
    __syncthreads();
    half8v ah[2], bh[4];
#pragma unroll
    for (int mi = 0; mi < 2; ++mi)
      ah[mi] = *(const half8v*)&As[wave * 32 + mi * 16 + fm][fq * 8];
#pragma unroll
    for (int ni = 0; ni < 4; ++ni) bh[ni] = *(const half8v*)&Bs[ni * 16 + fm][fq * 8];
#pragma unroll
    for (int mi = 0; mi < 2; ++mi)
#pragma unroll
      for (int ni = 0; ni < 4; ++ni)
        acc[mi][ni] = __builtin_amdgcn_mfma_f32_16x16x32_f16(ah[mi], bh[ni], acc[mi][ni], 0, 0, 0);
    __syncthreads();
  }
  float lb1c[4], w20[4], w21[4];
#pragma unroll
  for (int ni = 0; ni < 4; ++ni) {
    int col = ni * 16 + fm;
    lb1c[ni] = lb1[col];
    w20[ni] = lw2[col * 2 + 0];
    w21[ni] = lw2[col * 2 + 1];
  }
  float b20 = lb2[0], b21 = lb2[1];
#pragma unroll
  for (int mi = 0; mi < 2; ++mi) {
#pragma unroll
    for (int r = 0; r < 4; ++r) {
      float v0 = 0.f, v1 = 0.f;
#pragma unroll
      for (int ni = 0; ni < 4; ++ni) {
        float s = fmaxf(acc[mi][ni][r] + lb1c[ni], 0.f);
        v0 = fmaf(s, w20[ni], v0);
        v1 = fmaf(s, w21[ni], v1);
      }
#pragma unroll
      for (int o = 1; o < 16; o <<= 1) {
        v0 += __shfl_xor(v0, o);
        v1 += __shfl_xor(v1, o);
      }
      if (fm == 0) {
        int row = bm + wave * 32 + mi * 16 + fq * 4 + r;
        if (row < M) {
          v0 += b20;
          v1 += b21;
          float mx = fmaxf(v0, v1);
          float ls = mx + logf(expf(v0 - mx) + expf(v1 - mx));
          out[(long)row * 2 + 0] = v0 - ls;
          out[(long)row * 2 + 1] = v1 - ls;
        }
      }
    }
  }
}

// ---------------- per-node aggregation: r19 shape, no-max exp --------------
// One wave per node. lane: c = lane&31 (8-col group), hlf = lane>>5 (2 edges
// in flight), head4 = c>>3; logit lanes: h1 = lane&3, sl1 = lane>>2.
// alpha = exp(lrelu(l)) directly (max cancels in e/z; sigma~1.3, fp32-safe —
// verified r24). Keeps 28-VGPR occupancy (r24 lesson: TLP > ILP here).
__launch_bounds__(256)
__global__ void gat_aggregate_exp_kernel(const _Float16* __restrict__ h,
                                         const float* __restrict__ a_s,
                                         const float* __restrict__ a_d,
                                         const int* __restrict__ off,
                                         const int* __restrict__ csr_src,
                                         const float* __restrict__ bias,
                                         _Float16* __restrict__ outp, int N) {
  int wid = (blockIdx.x * blockDim.x + threadIdx.x) >> 6;
  int lane = threadIdx.x & 63;
  if (wid >= N) return;
  int c = lane & 31, hlf = lane >> 5, head4 = c >> 3;
  int h1 = lane & 3, sl1 = lane >> 2;
  int beg = off[wid], cnt = off[wid + 1] - beg;
  float ad_h1 = a_d[wid * 4 + h1];
  float psl = __expf(lrelu(a_s[wid * 4 + h1] + ad_h1));
  float pself = __shfl(psl, head4);
  float z = 0.f;
  float acc[8] = {};
  if (hlf == 0) {
    z = pself;
    half8v sr = *(const half8v*)(h + (long)wid * 256 + c * 8);
#pragma unroll
    for (int i = 0; i < 8; ++i) acc[i] = pself * (float)sr[i];
  }
  for (int c0 = 0; c0 < cnt; c0 += 16) {
    int i2 = c0 + (lane & 15);
    int sv = (i2 < cnt) ? csr_src[beg + i2] : 0;
    int i1 = c0 + sl1;
    int spi = __shfl(sv, sl1);
    float pv = (i1 < cnt) ? __expf(lrelu(a_s[(long)spi * 4 + h1] + ad_h1)) : 0.f;
#pragma unroll 4
    for (int j = 0; j < 16; j += 2) {
      if (c0 + j >= cnt) break;
      int e = j + hlf;
      int s = __shfl(sv, e);
      float p = __shfl(pv, e * 4 + head4);
      z += p;
      half8v rv = *(const half8v*)(h + (long)s * 256 + c * 8);
      acc[0] = fmaf(p, (float)rv[0], acc[0]);
      acc[1] = fmaf(p, (float)rv[1], acc[1]);
      acc[2] = fmaf(p, (float)rv[2], acc[2]);
      acc[3] = fmaf(p, (float)rv[3], acc[3]);
      acc[4] = fmaf(p, (float)rv[4], acc[4]);
      acc[5] = fmaf(p, (float)rv[5], acc[5]);
      acc[6] = fmaf(p, (float)rv[6], acc[6]);
      acc[7] = fmaf(p, (float)rv[7], acc[7]);
    }
  }
  z += __shfl_xor(z, 32);
#pragma unroll
  for (int i = 0; i < 8; ++i) acc[i] += __shfl_xor(acc[i], 32);
  if (hlf == 0) {
    float inv = 1.f / z;  // z >= pself > 0
    half8v o;
#pragma unroll
    for (int i = 0; i < 8; ++i) o[i] = (_Float16)elu1(fmaf(acc[i], inv, bias[c * 8 + i]));
    *(half8v*)(outp + (long)wid * 256 + c * 8) = o;
  }
}

// ---------------------------------------------------------------------------
static inline int cdiv(int a, int b) { return (a + b - 1) / b; }

extern "C" void kernel_launch(void* const* d_in, const int* in_sizes, int n_in,
                              void* d_out, int out_size, void* d_ws, size_t ws_size,
                              hipStream_t stream) {
  const float* x = (const float*)d_in[0];
  const int* ei = (const int*)d_in[1];
  const float* W1 = (const float*)d_in[2];
  const float* as1 = (const float*)d_in[3];
  const float* ad1 = (const float*)d_in[4];
  const float* b1 = (const float*)d_in[5];
  const float* W2 = (const float*)d_in[6];
  const float* as2 = (const float*)d_in[7];
  const float* ad2 = (const float*)d_in[8];
  const float* b2 = (const float*)d_in[9];
  const float* lw1 = (const float*)d_in[10];
  const float* lb1 = (const float*)d_in[11];
  const float* lw2 = (const float*)d_in[12];
  const float* lb2 = (const float*)d_in[13];
  float* out = (float*)d_out;

  int N = in_sizes[0] / 128;  // 50000
  int E = in_sizes[1] / 2;    // 800000
  int Mp = cdiv(N, 128) * 128;  // 50048 (divisible by 128)

  char* ws = (char*)d_ws;
  _Float16* Wt1 = (_Float16*)ws; ws += 256 * 128 * 2;
  _Float16* Wt2 = (_Float16*)ws; ws += 256 * 256 * 2;
  _Float16* WL = (_Float16*)ws; ws += 64 * 256 * 2;
  _Float16* C = (_Float16*)ws; ws += (size_t)Mp * 256 * 2;   // GEMM out
  _Float16* h2 = (_Float16*)ws; ws += (size_t)Mp * 256 * 2;  // aggregate out
  float* aS = (float*)ws; ws += (size_t)N * 4 * 4;
  float* aD = (float*)ws; ws += (size_t)N * 4 * 4;
  int* csr_src = (int*)ws; ws += (size_t)E * 4;
  int* indeg = (int*)ws; ws += (size_t)N * 4;
  int* cursor = (int*)ws; ws += (size_t)N * 4;
  int* off = (int*)ws; ws += (size_t)(N + 4) * 4;
  int* incl = (int*)ws; ws += (size_t)N * 4;
  int* bsum = (int*)ws; ws += 64 * 4;

  const int* e_src = ei;
  const int* e_dst = ei + E;
  int nb = cdiv(N, 1024);

  // weight conversion + indeg zeroing (one launch)
  convert_weights_kernel<<<cdiv(114688 + N, 256), 256, 0, stream>>>(W1, W2, lw1, Wt1, Wt2, WL,
                                                                    indeg, N);

  // CSR build
  count_kernel<<<cdiv(E, 256), 256, 0, stream>>>(e_dst, E, indeg);
  scan_block_kernel<<<nb, 1024, 0, stream>>>(indeg, incl, bsum, N);
  scan_finalize_kernel<<<cdiv(N, 256), 256, 0, stream>>>(indeg, incl, bsum, off, cursor, N);
  fill_kernel<<<cdiv(E, 256), 256, 0, stream>>>(e_src, e_dst, E, cursor, csr_src);

  // Layer 1 (K=128, fp32 A converted in staging)
  mfma_gemm_attn_kernel<float><<<dim3(2, Mp / 128), 256, 0, stream>>>(x, Wt1, as1, ad1, C, aS, aD,
                                                                      N, 128);
  gat_aggregate_exp_kernel<<<cdiv(N, 4), 256, 0, stream>>>(C, aS, aD, off, csr_src, b1, h2, N);

  // Layer 2 (K=256, fp16 A)
  mfma_gemm_attn_kernel<_Float16><<<dim3(2, Mp / 128), 256, 0, stream>>>(h2, Wt2, as2, ad2, C, aS,
                                                                         aD, N, 256);
  gat_aggregate_exp_kernel<<<cdiv(N, 4), 256, 0, stream>>>(C, aS, aD, off, csr_src, b2, h2, N);

  // Head (MFMA, fused epilogue, 128-row tile)
  head_mfma_kernel<<<Mp / 128, 256, 0, stream>>>(h2, WL, lb1, lw2, lb2, out, N);
}